// Round 7
// baseline (119.749 us; speedup 1.0000x reference)
//
#include <hip/hip_runtime.h>
#include <hip/hip_bf16.h>

typedef __bf16 bf16x8 __attribute__((ext_vector_type(8)));
typedef float  f32x4  __attribute__((ext_vector_type(4)));
typedef float  f4     __attribute__((ext_vector_type(4)));
typedef unsigned short us4 __attribute__((ext_vector_type(4)));
typedef unsigned short us8 __attribute__((ext_vector_type(8)));

__device__ inline unsigned short f2bf(float f) {
  union { float f; unsigned int u; } v; v.f = f;
  unsigned int r = v.u + 0x7fffu + ((v.u >> 16) & 1u);
  return (unsigned short)(r >> 16);
}
__device__ inline float bf2f(unsigned short u) {
  union { unsigned int u; float f; } v; v.u = (unsigned int)u << 16;
  return v.f;
}

__device__ inline void gload_lds16(const void* g, void* l) {
  __builtin_amdgcn_global_load_lds((const __attribute__((address_space(1))) void*)g,
                                   (__attribute__((address_space(3))) void*)l, 16, 0, 0);
}

// ------- fused: fp32->bf16 convert of x  +  W transpose/concat to bf16 -------
// blocks [0,3072): convx (x float4 per thread). blocks [3072,4800): convw.
__global__ __launch_bounds__(256) void convfused(const float* __restrict__ x,
                                                 const float* __restrict__ Wq,
                                                 const float* __restrict__ Wk,
                                                 const float* __restrict__ Wv,
                                                 unsigned short* __restrict__ xb,
                                                 unsigned short* __restrict__ wt) {
  __shared__ unsigned short tile[32][33];
  if (blockIdx.x < 3072) {
    int i = blockIdx.x * 256 + threadIdx.x;       // indexes float4
    f4 v = ((const f4*)x)[i];
    us4 o;
    #pragma unroll
    for (int c = 0; c < 4; ++c) o[c] = f2bf(v[c]);
    ((us4*)xb)[i] = o;
  } else {
    int b = blockIdx.x - 3072;                    // 0..1727 = 3 * 24 * 24
    int bz = b / 576, rem = b % 576;
    int bx = rem / 24, by = rem % 24;
    const float* W = bz == 0 ? Wq : (bz == 1 ? Wk : Wv);
    int k0 = bx * 32, n0 = by * 32;
    int c = threadIdx.x & 31, r8 = threadIdx.x >> 5;
    #pragma unroll
    for (int p = 0; p < 4; ++p) {
      int r = p * 8 + r8;
      tile[r][c] = f2bf(W[(size_t)(k0 + r) * 768 + n0 + c]);
    }
    __syncthreads();
    #pragma unroll
    for (int p = 0; p < 4; ++p) {
      int r = p * 8 + r8;  // n index
      wt[((size_t)bz * 768 + n0 + r) * 768 + k0 + c] = tile[c][r];
    }
  }
}

// ------- V columns of QKV -> Vt[768][4096] bf16 -------
__global__ __launch_bounds__(256) void transv(const unsigned short* __restrict__ qkv,
                                              unsigned short* __restrict__ vt) {
  __shared__ unsigned short tile[32][33];
  int s0 = blockIdx.x * 32, d0 = blockIdx.y * 32;
  int c = threadIdx.x & 31, r8 = threadIdx.x >> 5;
  #pragma unroll
  for (int p = 0; p < 4; ++p) {
    int r = p * 8 + r8;  // s index
    tile[r][c] = qkv[(size_t)(s0 + r) * 2304 + 1536 + d0 + c];
  }
  __syncthreads();
  #pragma unroll
  for (int p = 0; p < 4; ++p) {
    int r = p * 8 + r8;  // d index
    vt[(size_t)(d0 + r) * 4096 + s0 + c] = tile[c][r];
  }
}

// ======== deep-pipelined bf16 GEMM (ring-RING K32 subtiles), C = A @ B^T ========
// BM = BN = WAVES*32, threads = WAVES*64 (staging invariant: threads == BM+BN).
// Ring safety: stage at step s targets slot (s+RING-1)%RING, whose previous
// reader was step s-1 (all waves' ds_reads complete before the step-s barrier);
// counted vmcnt forces a slot's loads landed RING-2 steps after issue, before read.
// RING=4: vmcnt 8/4/0 tail; RING=3: vmcnt 4/0 tail.
// LDS swizzle (st_16x32): byte ^ (((row>>3)&1)<<5); staging pre-swizzles the GLOBAL
// source so linear global_load_lds lands swizzled (rule 21).
// DOEXP: epilogue v = exp(v*cscale) (unnormalized softmax numerator).
// DOSCALE: epilogue v *= rowinv[r] (softmax denominator, commuted through PV).
// Split-K: gridDim.y slice y computes K range [y*kspan,(y+1)*kspan) -> C[y].
template <int WAVES, int WM, int WN, int RING, int MINW, typename OUT_T, bool DOEXP, bool DOSCALE>
__global__ __launch_bounds__(WAVES * 64, MINW) void gemmdp(const unsigned short* __restrict__ A,
                                                           const unsigned short* __restrict__ B,
                                                           OUT_T* __restrict__ C0,
                                                           OUT_T* __restrict__ C1,
                                                           OUT_T* __restrict__ C2,
                                                           OUT_T* __restrict__ C3,
                                                           const float* __restrict__ rowinv,
                                                           int lda, int ldb, int ldc, int kspan,
                                                           int nbx, float cscale) {
  constexpr int BM = WAVES * 32, BN = WAVES * 32;
  constexpr int MF = 2 * WAVES / WM, NF = 2 * WAVES / WN;
  constexpr int SLOT = (BM + BN) * 64;
  __shared__ __align__(16) char lds[RING * SLOT];
  const int tid = threadIdx.x;
  const int w = tid >> 6, l = tid & 63;
  const int wr = w / WN, wc = w % WN;
  const int lr = l & 15, lk = l >> 4;

  const int nwg = gridDim.x;             // bijective XCD swizzle (nwg % 8 == 0)
  const int swz = (blockIdx.x & 7) * (nwg >> 3) + (blockIdx.x >> 3);
  const int bx = swz % nbx, by = swz / nbx;
  const int m0 = by * BM, n0 = bx * BN;
  const int koff0 = blockIdx.y * kspan;
  OUT_T* __restrict__ C = blockIdx.y == 0 ? C0 : (blockIdx.y == 1 ? C1 : (blockIdx.y == 2 ? C2 : C3));

  f32x4 acc[MF][NF] = {};

  // --- staging: thread covers 4x 16B chunks (A rows trow, trow+BM/2; B same) ---
  const int trow = tid >> 2;
  const int koff = ((tid & 3) * 8) ^ (((tid >> 5) & 1) * 16);  // inverse-swizzled source k
  const unsigned short* gA0 = A + (size_t)(m0 + trow) * lda + koff + koff0;
  const unsigned short* gA1 = A + (size_t)(m0 + BM / 2 + trow) * lda + koff + koff0;
  const unsigned short* gB0 = B + (size_t)(n0 + trow) * ldb + koff + koff0;
  const unsigned short* gB1 = B + (size_t)(n0 + BN / 2 + trow) * ldb + koff + koff0;
  const int wave16 = (tid & ~63) * 16;   // wave-uniform LDS chunk base

  auto stage = [&](int slot, int k0) {
    char* base = lds + slot * SLOT;
    gload_lds16(gA0 + k0, base + wave16);
    gload_lds16(gA1 + k0, base + BM * 32 + wave16);
    gload_lds16(gB0 + k0, base + BM * 64 + wave16);
    gload_lds16(gB1 + k0, base + BM * 64 + BN * 32 + wave16);
  };

  // --- fragment read offsets (within slot); xor bit5 by (row>>3)&1 ---
  const int xorv = ((l >> 3) & 1) << 5;
  const int aoff = (wr * (MF * 16) + lr) * 64 + lk * 16;            // + mf*1024
  const int boff = BM * 64 + (wc * (NF * 16) + lr) * 64 + lk * 16;  // + nf*1024

  const int nsteps = kspan >> 5;
  #pragma unroll
  for (int j = 0; j < RING - 1; ++j) stage(j, j * 32);

  int rdslot = 0, stslot = RING - 1;
  for (int s = 0; s < nsteps; ++s) {
    __builtin_amdgcn_sched_barrier(0);
    if constexpr (RING == 4) {
      if (s < nsteps - 2)       asm volatile("s_waitcnt vmcnt(8)" ::: "memory");
      else if (s == nsteps - 2) asm volatile("s_waitcnt vmcnt(4)" ::: "memory");
      else                      asm volatile("s_waitcnt vmcnt(0)" ::: "memory");
    } else {
      if (s < nsteps - 1)       asm volatile("s_waitcnt vmcnt(4)" ::: "memory");
      else                      asm volatile("s_waitcnt vmcnt(0)" ::: "memory");
    }
    __builtin_amdgcn_s_barrier();
    __builtin_amdgcn_sched_barrier(0);

    if (s + RING - 1 < nsteps) stage(stslot, (s + RING - 1) << 5);  // slot last read at s-1

    const char* sb = lds + rdslot * SLOT;
    bf16x8 fa[MF], fb[NF];
    #pragma unroll
    for (int mf = 0; mf < MF; ++mf)
      fa[mf] = *(const bf16x8*)(sb + ((aoff + mf * 1024) ^ xorv));
    #pragma unroll
    for (int nf = 0; nf < NF; ++nf)
      fb[nf] = *(const bf16x8*)(sb + ((boff + nf * 1024) ^ xorv));

    __builtin_amdgcn_s_setprio(1);
    #pragma unroll
    for (int mf = 0; mf < MF; ++mf)
      #pragma unroll
      for (int nf = 0; nf < NF; ++nf)
        acc[mf][nf] = __builtin_amdgcn_mfma_f32_16x16x32_bf16(fa[mf], fb[nf], acc[mf][nf], 0, 0, 0);
    __builtin_amdgcn_s_setprio(0);

    rdslot = (rdslot + 1 == RING) ? 0 : rdslot + 1;
    stslot = (stslot + 1 == RING) ? 0 : stslot + 1;
  }

  #pragma unroll
  for (int mf = 0; mf < MF; ++mf)
    #pragma unroll
    for (int nf = 0; nf < NF; ++nf)
      #pragma unroll
      for (int i = 0; i < 4; ++i) {
        int r = m0 + wr * (MF * 16) + mf * 16 + lk * 4 + i;
        int c = n0 + wc * (NF * 16) + nf * 16 + lr;
        float v = acc[mf][nf][i] * cscale;
        if constexpr (DOEXP)   v = __expf(v);
        if constexpr (DOSCALE) v *= rowinv[r];
        if constexpr (__is_same(OUT_T, unsigned short)) C[(size_t)r * ldc + c] = f2bf(v);
        else                                            C[(size_t)r * ldc + c] = v;
      }
}

// ------- rowinv[r] = 1 / sum(P[r][:]) ; P bf16 [4096][4096], one wave per row -------
__global__ __launch_bounds__(256) void rowsum(const unsigned short* __restrict__ P,
                                              float* __restrict__ rowinv) {
  const int wv = threadIdx.x >> 6, l = threadIdx.x & 63;
  const int r = blockIdx.x * 4 + wv;
  const unsigned short* row = P + (size_t)r * 4096;
  float sum = 0.f;
  #pragma unroll
  for (int j = 0; j < 8; ++j) {
    us8 v = ((const us8*)row)[l + j * 64];
    #pragma unroll
    for (int c = 0; c < 8; ++c) sum += bf2f(v[c]);
  }
  #pragma unroll
  for (int o = 32; o > 0; o >>= 1) sum += __shfl_xor(sum, o);
  if (l == 0) rowinv[r] = 1.f / sum;
}

// ------- out += p1 + p2 + p3 (f4 elementwise, fixed order: deterministic) -------
__global__ __launch_bounds__(256) void reduce_add4(float* __restrict__ out,
                                                   const float* __restrict__ p1,
                                                   const float* __restrict__ p2,
                                                   const float* __restrict__ p3) {
  int i = blockIdx.x * 256 + threadIdx.x;
  f4 a = ((const f4*)out)[i];
  f4 b = ((const f4*)p1)[i];
  f4 c = ((const f4*)p2)[i];
  f4 d = ((const f4*)p3)[i];
  #pragma unroll
  for (int k = 0; k < 4; ++k) a[k] += b[k] + c[k] + d[k];
  ((f4*)out)[i] = a;
}

extern "C" void kernel_launch(void* const* d_in, const int* in_sizes, int n_in,
                              void* d_out, int out_size, void* d_ws, size_t ws_size,
                              hipStream_t stream) {
  const float* x  = (const float*)d_in[0];
  const float* Wq = (const float*)d_in[1];
  const float* Wk = (const float*)d_in[2];
  const float* Wv = (const float*)d_in[3];
  float* out = (float*)d_out;
  char* ws = (char*)d_ws;

  // ws layout (bytes):
  //   [0, 18874368)            qkv bf16 [4096][2304]; dead after QK gemm ->
  //                            reused as PV split-K partial p1 fp32 [4096][768] (12.58MB)
  //   [18874368, 52428800)     P bf16 [4096][4096] (unnormalized exp(scores))
  //       xb (6.3MB) and wt (3.5MB) alias this region; both dead before QK writes P
  //   [52428800, 58720256)     Vt bf16 [768][4096]
  //   [58720256, 58736640)     rowinv fp32 [4096]
  //   [58736640, 83902464)     PV partials p2, p3 fp32 [4096][768] each
  unsigned short* qkv = (unsigned short*)ws;
  unsigned short* P   = (unsigned short*)(ws + 18874368);
  unsigned short* xb  = (unsigned short*)(ws + 18874368);
  unsigned short* wt  = (unsigned short*)(ws + 18874368 + 6291456);
  unsigned short* vt  = (unsigned short*)(ws + 52428800);
  float* rowinvp      = (float*)(ws + 58720256);
  float* p1           = (float*)ws;                    // aliases qkv (dead by then)
  float* p2           = (float*)(ws + 58736640);
  float* p3           = (float*)(ws + 58736640 + 12582912);

  const float qscale = 0.03608439182435161f;  // 1/sqrt(768)

  convfused<<<4800, 256, 0, stream>>>(x, Wq, Wk, Wv, xb, wt);
  // QKV = x @ [Wq|Wk|Wv]   (M=4096, N=2304, K=768), 128x128 tiles -> 576 blocks,
  //   ring-3 (48KB LDS -> 3 blocks/CU, all 576 co-resident)
  gemmdp<4, 2, 2, 3, 3, unsigned short, false, false><<<576, 256, 0, stream>>>(
      xb, wt, qkv, qkv, qkv, qkv, nullptr, 768, 768, 2304, 768, 18, 1.0f);
  transv<<<dim3(128, 24), 256, 0, stream>>>(qkv, vt);
  // P = exp((Q @ K^T) * qscale)  (M=4096, N=4096, K=768), 256x256 -> 256 blocks, ring-4
  gemmdp<8, 2, 4, 4, 2, unsigned short, true, false><<<256, 512, 0, stream>>>(
      qkv, qkv + 768, P, P, P, P, nullptr, 2304, 2304, 4096, 768, 16, qscale);
  // rowinv = 1 / row-sums of P
  rowsum<<<1024, 256, 0, stream>>>(P, rowinvp);
  // out = (P @ V) * rowinv (M=4096, N=768, K=4096), 128x128 tiles, split-K=4, ring-3
  //   (192,4) = 768 blocks = exactly 3/CU, all co-resident; slices -> out,p1,p2,p3
  gemmdp<4, 2, 2, 3, 3, float, false, true><<<dim3(192, 4), 256, 0, stream>>>(
      P, vt, out, p1, p2, p3, rowinvp, 4096, 4096, 768, 1024, 6, 1.0f);
  reduce_add4<<<3072, 256, 0, stream>>>(out, p1, p2, p3);
}

// Round 8
// 117.793 us; speedup vs baseline: 1.0166x; 1.0166x over previous
//
#include <hip/hip_runtime.h>
#include <hip/hip_bf16.h>

typedef __bf16 bf16x8 __attribute__((ext_vector_type(8)));
typedef float  f32x4  __attribute__((ext_vector_type(4)));
typedef float  f4     __attribute__((ext_vector_type(4)));
typedef unsigned short us4 __attribute__((ext_vector_type(4)));
typedef unsigned short us8 __attribute__((ext_vector_type(8)));

__device__ inline unsigned short f2bf(float f) {
  union { float f; unsigned int u; } v; v.f = f;
  unsigned int r = v.u + 0x7fffu + ((v.u >> 16) & 1u);
  return (unsigned short)(r >> 16);
}
__device__ inline float bf2f(unsigned short u) {
  union { unsigned int u; float f; } v; v.u = (unsigned int)u << 16;
  return v.f;
}

__device__ inline void gload_lds16(const void* g, void* l) {
  __builtin_amdgcn_global_load_lds((const __attribute__((address_space(1))) void*)g,
                                   (__attribute__((address_space(3))) void*)l, 16, 0, 0);
}

// ------- fused: fp32->bf16 convert of x  +  W transpose/concat to bf16 -------
__global__ __launch_bounds__(256) void convfused(const float* __restrict__ x,
                                                 const float* __restrict__ Wq,
                                                 const float* __restrict__ Wk,
                                                 const float* __restrict__ Wv,
                                                 unsigned short* __restrict__ xb,
                                                 unsigned short* __restrict__ wt) {
  __shared__ unsigned short tile[32][33];
  if (blockIdx.x < 3072) {
    int i = blockIdx.x * 256 + threadIdx.x;       // indexes float4
    f4 v = ((const f4*)x)[i];
    us4 o;
    #pragma unroll
    for (int c = 0; c < 4; ++c) o[c] = f2bf(v[c]);
    ((us4*)xb)[i] = o;
  } else {
    int b = blockIdx.x - 3072;                    // 0..1727 = 3 * 24 * 24
    int bz = b / 576, rem = b % 576;
    int bx = rem / 24, by = rem % 24;
    const float* W = bz == 0 ? Wq : (bz == 1 ? Wk : Wv);
    int k0 = bx * 32, n0 = by * 32;
    int c = threadIdx.x & 31, r8 = threadIdx.x >> 5;
    #pragma unroll
    for (int p = 0; p < 4; ++p) {
      int r = p * 8 + r8;
      tile[r][c] = f2bf(W[(size_t)(k0 + r) * 768 + n0 + c]);
    }
    __syncthreads();
    #pragma unroll
    for (int p = 0; p < 4; ++p) {
      int r = p * 8 + r8;  // n index
      wt[((size_t)bz * 768 + n0 + r) * 768 + k0 + c] = tile[c][r];
    }
  }
}

// ------- V columns of QKV -> Vt[768][4096] bf16 -------
__global__ __launch_bounds__(256) void transv(const unsigned short* __restrict__ qkv,
                                              unsigned short* __restrict__ vt) {
  __shared__ unsigned short tile[32][33];
  int s0 = blockIdx.x * 32, d0 = blockIdx.y * 32;
  int c = threadIdx.x & 31, r8 = threadIdx.x >> 5;
  #pragma unroll
  for (int p = 0; p < 4; ++p) {
    int r = p * 8 + r8;  // s index
    tile[r][c] = qkv[(size_t)(s0 + r) * 2304 + 1536 + d0 + c];
  }
  __syncthreads();
  #pragma unroll
  for (int p = 0; p < 4; ++p) {
    int r = p * 8 + r8;  // d index
    vt[(size_t)(d0 + r) * 4096 + s0 + c] = tile[c][r];
  }
}

// ======== deep-pipelined bf16 GEMM: ring-4 K32 slots + register read-ahead ========
// BM = BN = WAVES*32, threads = WAVES*64 (staging invariant: threads == BM+BN).
// Step s: vmcnt(4) -> barrier -> stage slot (s+3)&3 -> PREFETCH frags of slot
// (s+1)&3 into the alternate register set -> MFMA on current set. After the
// barrier, this step's MFMAs consume registers loaded LAST step (lgkmcnt only,
// no LDS latency exposure). Unrolled x2 with named ping-pong sets (rule #20).
// Hazards: stage(s) writes slot (s-1)&3, last read at step s-2, completion
// forced by lgkmcnt before MFMA(s-1), ordered by the step-s barrier. vmcnt(4)
// at step s forces the stage issued at s-2 (slot s+1) landed before prefetch.
// Requires nsteps even (kspan % 64 == 0).
// LDS swizzle (st_16x32): byte ^ (((row>>3)&1)<<5); staging pre-swizzles the
// GLOBAL source so linear global_load_lds lands swizzled (rule 21).
// DOEXP: epilogue v = exp(v*cscale). DOSCALE: epilogue v *= rowinv[r].
// Split-K: gridDim.y slice y computes K range [y*kspan,(y+1)*kspan) -> C0/C1.
template <int WAVES, int WM, int WN, int MINW, typename OUT_T, bool DOEXP, bool DOSCALE>
__global__ __launch_bounds__(WAVES * 64, MINW) void gemmdp(const unsigned short* __restrict__ A,
                                                           const unsigned short* __restrict__ B,
                                                           OUT_T* __restrict__ C0,
                                                           OUT_T* __restrict__ C1,
                                                           const float* __restrict__ rowinv,
                                                           int lda, int ldb, int ldc, int kspan,
                                                           int nbx, float cscale) {
  constexpr int BM = WAVES * 32, BN = WAVES * 32;
  constexpr int MF = 2 * WAVES / WM, NF = 2 * WAVES / WN;
  constexpr int SLOT = (BM + BN) * 64;
  __shared__ __align__(16) char lds[4 * SLOT];
  const int tid = threadIdx.x;
  const int w = tid >> 6, l = tid & 63;
  const int wr = w / WN, wc = w % WN;
  const int lr = l & 15, lk = l >> 4;

  const int nwg = gridDim.x;             // bijective XCD swizzle (nwg % 8 == 0)
  const int swz = (blockIdx.x & 7) * (nwg >> 3) + (blockIdx.x >> 3);
  const int bx = swz % nbx, by = swz / nbx;
  const int m0 = by * BM, n0 = bx * BN;
  const int koff0 = blockIdx.y * kspan;
  OUT_T* __restrict__ C = blockIdx.y ? C1 : C0;

  f32x4 acc[MF][NF] = {};

  // --- staging: thread covers 4x 16B chunks (A rows trow, trow+BM/2; B same) ---
  const int trow = tid >> 2;
  const int koff = ((tid & 3) * 8) ^ (((tid >> 5) & 1) * 16);  // inverse-swizzled source k
  const unsigned short* gA0 = A + (size_t)(m0 + trow) * lda + koff + koff0;
  const unsigned short* gA1 = A + (size_t)(m0 + BM / 2 + trow) * lda + koff + koff0;
  const unsigned short* gB0 = B + (size_t)(n0 + trow) * ldb + koff + koff0;
  const unsigned short* gB1 = B + (size_t)(n0 + BN / 2 + trow) * ldb + koff + koff0;
  const int wave16 = (tid & ~63) * 16;   // wave-uniform LDS chunk base

  auto stage = [&](int slot, int k0) {
    char* base = lds + slot * SLOT;
    gload_lds16(gA0 + k0, base + wave16);
    gload_lds16(gA1 + k0, base + BM * 32 + wave16);
    gload_lds16(gB0 + k0, base + BM * 64 + wave16);
    gload_lds16(gB1 + k0, base + BM * 64 + BN * 32 + wave16);
  };

  // --- fragment read offsets (within slot); xor bit5 by (row>>3)&1 ---
  const int xorv = ((l >> 3) & 1) << 5;
  const int aoff = (wr * (MF * 16) + lr) * 64 + lk * 16;            // + mf*1024
  const int boff = BM * 64 + (wc * (NF * 16) + lr) * 64 + lk * 16;  // + nf*1024

  auto ldfrags = [&](int slot, bf16x8 (&pa)[MF], bf16x8 (&pb)[NF]) {
    const char* sb = lds + slot * SLOT;
    #pragma unroll
    for (int mf = 0; mf < MF; ++mf)
      pa[mf] = *(const bf16x8*)(sb + ((aoff + mf * 1024) ^ xorv));
    #pragma unroll
    for (int nf = 0; nf < NF; ++nf)
      pb[nf] = *(const bf16x8*)(sb + ((boff + nf * 1024) ^ xorv));
  };

  const int nsteps = kspan >> 5;         // even by construction
  bf16x8 fa[MF], fb[NF], ga[MF], gb[NF];

  stage(0, 0); stage(1, 32); stage(2, 64);
  asm volatile("s_waitcnt vmcnt(8)" ::: "memory");   // slot 0 landed (own wave)
  __builtin_amdgcn_s_barrier();                      // slot 0 landed (all waves)
  ldfrags(0, fa, fb);                                // prefetch step-0 frags

  auto step = [&](int s, bf16x8 (&ca)[MF], bf16x8 (&cb)[NF],
                  bf16x8 (&xa)[MF], bf16x8 (&xb2)[NF]) {
    __builtin_amdgcn_sched_barrier(0);
    if (s < nsteps - 2) asm volatile("s_waitcnt vmcnt(4)" ::: "memory");
    else                asm volatile("s_waitcnt vmcnt(0)" ::: "memory");
    __builtin_amdgcn_s_barrier();
    __builtin_amdgcn_sched_barrier(0);

    if (s + 3 < nsteps) stage((s + 3) & 3, (s + 3) << 5);  // slot (s-1)&3, read done @s-2
    if (s + 1 < nsteps) ldfrags((s + 1) & 3, xa, xb2);     // prefetch next step's frags

    __builtin_amdgcn_s_setprio(1);
    #pragma unroll
    for (int mf = 0; mf < MF; ++mf)
      #pragma unroll
      for (int nf = 0; nf < NF; ++nf)
        acc[mf][nf] = __builtin_amdgcn_mfma_f32_16x16x32_bf16(ca[mf], cb[nf], acc[mf][nf], 0, 0, 0);
    __builtin_amdgcn_s_setprio(0);
  };

  for (int s = 0; s < nsteps; s += 2) {
    step(s,     fa, fb, ga, gb);   // consume fa/fb, prefetch into ga/gb
    step(s + 1, ga, gb, fa, fb);   // consume ga/gb, prefetch into fa/fb
  }

  #pragma unroll
  for (int mf = 0; mf < MF; ++mf)
    #pragma unroll
    for (int nf = 0; nf < NF; ++nf)
      #pragma unroll
      for (int i = 0; i < 4; ++i) {
        int r = m0 + wr * (MF * 16) + mf * 16 + lk * 4 + i;
        int c = n0 + wc * (NF * 16) + nf * 16 + lr;
        float v = acc[mf][nf][i] * cscale;
        if constexpr (DOEXP)   v = __expf(v);
        if constexpr (DOSCALE) v *= rowinv[r];
        if constexpr (__is_same(OUT_T, unsigned short)) C[(size_t)r * ldc + c] = f2bf(v);
        else                                            C[(size_t)r * ldc + c] = v;
      }
}

// ------- rowinv[r] = 1 / sum(P[r][:]) ; P bf16 [4096][4096], one wave per row -------
__global__ __launch_bounds__(256) void rowsum(const unsigned short* __restrict__ P,
                                              float* __restrict__ rowinv) {
  const int wv = threadIdx.x >> 6, l = threadIdx.x & 63;
  const int r = blockIdx.x * 4 + wv;
  const unsigned short* row = P + (size_t)r * 4096;
  float sum = 0.f;
  #pragma unroll
  for (int j = 0; j < 8; ++j) {
    us8 v = ((const us8*)row)[l + j * 64];
    #pragma unroll
    for (int c = 0; c < 8; ++c) sum += bf2f(v[c]);
  }
  #pragma unroll
  for (int o = 32; o > 0; o >>= 1) sum += __shfl_xor(sum, o);
  if (l == 0) rowinv[r] = 1.f / sum;
}

// ------- out += p1 (f4 elementwise) -------
__global__ __launch_bounds__(256) void reduce_add(float* __restrict__ out,
                                                  const float* __restrict__ p1) {
  int i = blockIdx.x * 256 + threadIdx.x;
  f4 a = ((const f4*)out)[i];
  f4 b = ((const f4*)p1)[i];
  #pragma unroll
  for (int c = 0; c < 4; ++c) a[c] += b[c];
  ((f4*)out)[i] = a;
}

extern "C" void kernel_launch(void* const* d_in, const int* in_sizes, int n_in,
                              void* d_out, int out_size, void* d_ws, size_t ws_size,
                              hipStream_t stream) {
  const float* x  = (const float*)d_in[0];
  const float* Wq = (const float*)d_in[1];
  const float* Wk = (const float*)d_in[2];
  const float* Wv = (const float*)d_in[3];
  float* out = (float*)d_out;
  char* ws = (char*)d_ws;

  // ws layout (bytes):
  //   [0, 18874368)            qkv bf16 [4096][2304]; dead after QK gemm ->
  //                            reused as PV split-K partial p1 fp32 [4096][768]
  //   [18874368, 52428800)     P bf16 [4096][4096] (unnormalized exp(scores))
  //       xb (6.3MB) and wt (3.5MB) alias this region; both dead before QK writes P
  //   [52428800, 58720256)     Vt bf16 [768][4096]
  //   [58720256, 58736640)     rowinv fp32 [4096]
  unsigned short* qkv = (unsigned short*)ws;
  unsigned short* P   = (unsigned short*)(ws + 18874368);
  unsigned short* xb  = (unsigned short*)(ws + 18874368);
  unsigned short* wt  = (unsigned short*)(ws + 18874368 + 6291456);
  unsigned short* vt  = (unsigned short*)(ws + 52428800);
  float* rowinvp      = (float*)(ws + 58720256);
  float* p1           = (float*)ws;                    // aliases qkv (dead by then)

  const float qscale = 0.03608439182435161f;  // 1/sqrt(768)

  convfused<<<4800, 256, 0, stream>>>(x, Wq, Wk, Wv, xb, wt);
  // QKV = x @ [Wq|Wk|Wv]   (M=4096, N=2304, K=768), 128x128 -> 576 blocks, ring-4+RA
  gemmdp<4, 2, 2, 2, unsigned short, false, false><<<576, 256, 0, stream>>>(
      xb, wt, qkv, qkv, nullptr, 768, 768, 2304, 768, 18, 1.0f);
  transv<<<dim3(128, 24), 256, 0, stream>>>(qkv, vt);
  // P = exp((Q @ K^T) * qscale)  (M=4096, N=4096, K=768), 256x256 -> 256 blocks, ring-4+RA
  gemmdp<8, 2, 4, 2, unsigned short, true, false><<<256, 512, 0, stream>>>(
      qkv, qkv + 768, P, P, nullptr, 2304, 2304, 4096, 768, 16, qscale);
  // rowinv = 1 / row-sums of P
  rowsum<<<1024, 256, 0, stream>>>(P, rowinvp);
  // out = (P @ V) * rowinv (M=4096, N=768, K=4096), 128x128, split-K=2, ring-4+RA
  //   (192,2) = 384 blocks, 2/CU -> all co-resident; slices -> out, p1
  gemmdp<4, 2, 2, 2, float, false, true><<<dim3(192, 2), 256, 0, stream>>>(
      P, vt, out, p1, rowinvp, 4096, 4096, 768, 2048, 6, 1.0f);
  reduce_add<<<3072, 256, 0, stream>>>(out, p1);
}